// Round 1
// baseline (824.327 us; speedup 1.0000x reference)
//
#include <hip/hip_runtime.h>
#include <cstdint>
#include <cstddef>

// ---------------------------------------------------------------------------
// AbsolutePositionalCrossAttention: B=16384, N=4, DIM=512, H=8, dh=64
// Pipeline:
//   1) transpose+cast weights fp32[K][N] -> bf16[N][K]   (tiny)
//   2) q  = x   @ Wq  + bq   -> bf16 [65536][512]   (MFMA GEMM, A fp32)
//   3) kv = ctx @ Wkv + bkv  -> bf16 [65536][1024]  (MFMA GEMM, A fp32)
//   4) attention per (batch, head): 4x4 masked softmax, in-place into q buffer
//   5) y  = attnout @ Wo + bo -> fp32 d_out         (MFMA GEMM, A bf16)
// ---------------------------------------------------------------------------

typedef __attribute__((ext_vector_type(8))) short short8;
typedef __attribute__((ext_vector_type(4))) float floatx4;

__device__ __forceinline__ unsigned short f2bf(float f) {
    unsigned u = __float_as_uint(f);
    unsigned r = 0x7fffu + ((u >> 16) & 1u);   // round-nearest-even
    return (unsigned short)((u + r) >> 16);
}
__device__ __forceinline__ float bf2f(unsigned short h) {
    return __uint_as_float(((unsigned)h) << 16);
}

// ---- weight transpose + cast: in fp32 [K][N] row-major -> out bf16 [N][K] --
__global__ void transpose_cast_kernel(const float* __restrict__ in,
                                      unsigned short* __restrict__ out,
                                      int K, int N) {
    __shared__ float tile[32][33];
    const int kb = blockIdx.x * 32, nb = blockIdx.y * 32;
    const int t = threadIdx.x, c = t & 31, r = t >> 5;  // 256 threads
#pragma unroll
    for (int i = 0; i < 4; ++i) {
        int kl = r + 8 * i;
        tile[kl][c] = in[(size_t)(kb + kl) * N + nb + c];
    }
    __syncthreads();
#pragma unroll
    for (int i = 0; i < 4; ++i) {
        int nl = r + 8 * i;
        out[(size_t)(nb + nl) * K + kb + c] = f2bf(tile[c][nl]);
    }
}

// ---- C[M][N] = A[M][K] @ Wt[N][K]^T + bias ---------------------------------
// 256 threads = 4 waves; block tile 128x128, BK=64; wave tile 64x64 (4x4 MFMA)
template <bool A_F32, bool OUT_F32>
__global__ __launch_bounds__(256, 2)
void gemm_bt_kernel(const void* __restrict__ Av,
                    const unsigned short* __restrict__ Wt,   // bf16 [N][K]
                    const float* __restrict__ bias,          // fp32 [N]
                    void* __restrict__ Cv,
                    int M, int N, int K) {
    constexpr int BM = 128, BN = 128, BK = 64, LDK = 72;  // pad: 144B stride
    __shared__ unsigned short As[BM][LDK];
    __shared__ unsigned short Bs[BN][LDK];
    const int t = threadIdx.x;
    const int wave = t >> 6, lane = t & 63;
    const int lm = lane & 15, quad = lane >> 4;
    const int n0 = (int)blockIdx.x * BN;    // col block
    const int row0 = (int)blockIdx.y * BM;  // row block
    const int wm = (wave & 1) * 64, wn = (wave >> 1) * 64;

    floatx4 acc[4][4] = {};

    for (int kb = 0; kb < K; kb += BK) {
        // ---- stage A tile (128x64) ----
        if (A_F32) {
            const float* A = (const float*)Av + (size_t)row0 * K + kb;
#pragma unroll
            for (int i = 0; i < 8; ++i) {
                int idx = i * 256 + t;            // float4 index
                int r = idx >> 4, c4 = (idx & 15) << 2;
                float4 v = *(const float4*)(A + (size_t)r * K + c4);
                uint2 p;
                p.x = (unsigned)f2bf(v.x) | ((unsigned)f2bf(v.y) << 16);
                p.y = (unsigned)f2bf(v.z) | ((unsigned)f2bf(v.w) << 16);
                *(uint2*)&As[r][c4] = p;
            }
        } else {
            const unsigned short* A = (const unsigned short*)Av + (size_t)row0 * K + kb;
#pragma unroll
            for (int i = 0; i < 4; ++i) {
                int idx = i * 256 + t;            // 8-elem chunk index
                int r = idx >> 3, c8 = (idx & 7) << 3;
                *(short8*)&As[r][c8] = *(const short8*)(A + (size_t)r * K + c8);
            }
        }
        // ---- stage B tile (128x64), always bf16 ----
        {
            const unsigned short* Bp = Wt + (size_t)n0 * K + kb;
#pragma unroll
            for (int i = 0; i < 4; ++i) {
                int idx = i * 256 + t;
                int r = idx >> 3, c8 = (idx & 7) << 3;
                *(short8*)&Bs[r][c8] = *(const short8*)(Bp + (size_t)r * K + c8);
            }
        }
        __syncthreads();
#pragma unroll
        for (int kk = 0; kk < BK; kk += 32) {
            short8 af[4], bfr[4];
#pragma unroll
            for (int mi = 0; mi < 4; ++mi)
                af[mi] = *(const short8*)&As[wm + mi * 16 + lm][kk + quad * 8];
#pragma unroll
            for (int ni = 0; ni < 4; ++ni)
                bfr[ni] = *(const short8*)&Bs[wn + ni * 16 + lm][kk + quad * 8];
#pragma unroll
            for (int mi = 0; mi < 4; ++mi)
#pragma unroll
                for (int ni = 0; ni < 4; ++ni)
                    acc[mi][ni] = __builtin_amdgcn_mfma_f32_16x16x32_bf16(
                        af[mi], bfr[ni], acc[mi][ni], 0, 0, 0);
        }
        __syncthreads();
    }
    // ---- epilogue: D lane layout col=lane&15, row=quad*4+r ----
#pragma unroll
    for (int ni = 0; ni < 4; ++ni) {
        int col = n0 + wn + ni * 16 + lm;
        float bv = bias[col];
#pragma unroll
        for (int mi = 0; mi < 4; ++mi) {
            int rowb = row0 + wm + mi * 16 + quad * 4;
#pragma unroll
            for (int r = 0; r < 4; ++r) {
                float v = acc[mi][ni][r] + bv;
                if (OUT_F32)
                    ((float*)Cv)[(size_t)(rowb + r) * N + col] = v;
                else
                    ((unsigned short*)Cv)[(size_t)(rowb + r) * N + col] = f2bf(v);
            }
        }
    }
}

// ---- attention: one wave per (batch, head); lane = dh index ---------------
// q: bf16 [65536][512] (overwritten in-place with attnout)
// kv: bf16 [65536][1024] (k | v)
__global__ __launch_bounds__(256)
void attn_kernel(unsigned short* __restrict__ q,
                 const unsigned short* __restrict__ kv) {
    const int t = threadIdx.x;
    const int wave = t >> 6, lane = t & 63;
    const int bh = (int)blockIdx.x * 4 + wave;  // b*8 + h
    const int b = bh >> 3, h = bh & 7;
    const float scale = 0.044194173824159216f;  // 512^-0.5
    const size_t qbase = (size_t)b * 2048 + h * 64 + lane;
    const size_t kvbase = (size_t)b * 4096 + h * 64 + lane;
    float qv[4], kk[4], vv[4];
#pragma unroll
    for (int i = 0; i < 4; ++i) {
        qv[i] = bf2f(q[qbase + (size_t)i * 512]);
        kk[i] = bf2f(kv[kvbase + (size_t)i * 1024]);
        vv[i] = bf2f(kv[kvbase + (size_t)i * 1024 + 512]);
    }
    float s[4][4];
#pragma unroll
    for (int i = 0; i < 4; ++i)
#pragma unroll
        for (int j = 0; j < 4; ++j) {
            float v = qv[i] * kk[j];
#pragma unroll
            for (int off = 32; off > 0; off >>= 1) v += __shfl_xor(v, off, 64);
            s[i][j] = v * scale;
        }
    // grid (0,0),(0,1),(1,0),(1,1): mask = dist<=1; bias where dist>1
    const float Mm[4][4] = {{1,1,1,0},{1,1,0,1},{1,0,1,1},{0,1,1,1}};
    const float Pp[4][4] = {{0,0,0,-1.6f},{0,0,-1.2f,0},{0,-0.8f,0,0},{-0.4f,0,0,0}};
#pragma unroll
    for (int i = 0; i < 4; ++i) {
        float tj[4], mx = -1e30f;
#pragma unroll
        for (int j = 0; j < 4; ++j) {
            tj[j] = s[i][j] * Mm[i][j] + Pp[i][j];
            mx = fmaxf(mx, tj[j]);
        }
        float e[4], sum = 0.f;
#pragma unroll
        for (int j = 0; j < 4; ++j) { e[j] = __expf(tj[j] - mx); sum += e[j]; }
        float inv = 1.f / sum;
        float od = 0.f;
#pragma unroll
        for (int j = 0; j < 4; ++j) od += e[j] * Mm[i][j] * vv[j];
        q[qbase + (size_t)i * 512] = f2bf(od * inv);
    }
}

// ---------------------------------------------------------------------------
extern "C" void kernel_launch(void* const* d_in, const int* in_sizes, int n_in,
                              void* d_out, int out_size, void* d_ws, size_t ws_size,
                              hipStream_t stream) {
    const float* x   = (const float*)d_in[0];
    const float* ctx = (const float*)d_in[1];
    const float* Wq  = (const float*)d_in[2];
    const float* bq  = (const float*)d_in[3];
    const float* Wkv = (const float*)d_in[4];
    const float* bkv = (const float*)d_in[5];
    const float* Wo  = (const float*)d_in[6];
    const float* bo  = (const float*)d_in[7];
    float* out = (float*)d_out;

    const int M = 65536;  // B*N rows
    unsigned short* WqT  = (unsigned short*)d_ws;               // 512*512
    unsigned short* WkvT = WqT + 512 * 512;                     // 1024*512
    unsigned short* WoT  = WkvT + 1024 * 512;                   // 512*512
    unsigned short* qbf  = WoT + 512 * 512;                     // M*512
    unsigned short* kvbf = qbf + (size_t)M * 512;               // M*1024

    dim3 b256(256);
    transpose_cast_kernel<<<dim3(16, 16), b256, 0, stream>>>(Wq, WqT, 512, 512);
    transpose_cast_kernel<<<dim3(16, 32), b256, 0, stream>>>(Wkv, WkvT, 512, 1024);
    transpose_cast_kernel<<<dim3(16, 16), b256, 0, stream>>>(Wo, WoT, 512, 512);

    gemm_bt_kernel<true, false><<<dim3(4, M / 128), b256, 0, stream>>>(
        x, WqT, bq, qbf, M, 512, 512);
    gemm_bt_kernel<true, false><<<dim3(8, M / 128), b256, 0, stream>>>(
        ctx, WkvT, bkv, kvbf, M, 1024, 512);

    attn_kernel<<<M * 8 / (4 * 4), b256, 0, stream>>>(qbf, kvbf);

    gemm_bt_kernel<false, true><<<dim3(4, M / 128), b256, 0, stream>>>(
        qbf, WoT, bo, out, M, 512, 512);
}

// Round 2
// 630.454 us; speedup vs baseline: 1.3075x; 1.3075x over previous
//
#include <hip/hip_runtime.h>
#include <cstdint>
#include <cstddef>

// ---------------------------------------------------------------------------
// AbsolutePositionalCrossAttention: B=16384, N=4, DIM=512, H=8, dh=64
//   1) transpose+cast weights -> WqkvT bf16 [1536][512], WoT bf16 [512][512]
//   2) cast x -> bf16;  q  = xbf @ WqT + bq   -> qkv[:, 0:512]
//   3) cast ctx -> bf16; kv = cbf @ WkvT + bkv -> qkv[:, 512:1536]
//   4) attention per (batch, head), in-place into qkv[:, 0:512]
//   5) out = qkv[:,0:512] @ WoT + bo -> fp32 d_out
// GEMM: 128x128 tile, BK=64, global_load_lds(16B) staging, XOR-swizzled LDS
// chunks (conflict-free ds_read_b128), XCD-aware block swizzle for L2 reuse.
// ---------------------------------------------------------------------------

typedef __attribute__((ext_vector_type(8))) short short8;
typedef __attribute__((ext_vector_type(4))) float floatx4;

__device__ __forceinline__ unsigned short f2bf(float f) {
    unsigned u = __float_as_uint(f);
    unsigned r = 0x7fffu + ((u >> 16) & 1u);   // round-nearest-even
    return (unsigned short)((u + r) >> 16);
}
__device__ __forceinline__ float bf2f(unsigned short h) {
    return __uint_as_float(((unsigned)h) << 16);
}

__device__ __forceinline__ void async_cp16(const unsigned short* g, unsigned short* l) {
    __builtin_amdgcn_global_load_lds(
        (const __attribute__((address_space(1))) unsigned int*)g,
        (__attribute__((address_space(3))) unsigned int*)l, 16, 0, 0);
}

// ---- weight transpose + cast: in fp32 [K][N] row-major -> out bf16 [N][K] --
__global__ void transpose_cast_kernel(const float* __restrict__ in,
                                      unsigned short* __restrict__ out,
                                      int K, int N) {
    __shared__ float tile[32][33];
    const int kb = blockIdx.x * 32, nb = blockIdx.y * 32;
    const int t = threadIdx.x, c = t & 31, r = t >> 5;  // 256 threads
#pragma unroll
    for (int i = 0; i < 4; ++i) {
        int kl = r + 8 * i;
        tile[kl][c] = in[(size_t)(kb + kl) * N + nb + c];
    }
    __syncthreads();
#pragma unroll
    for (int i = 0; i < 4; ++i) {
        int nl = r + 8 * i;
        out[(size_t)(nb + nl) * K + kb + c] = f2bf(tile[c][nl]);
    }
}

// ---- fp32 -> bf16 cast, 8 elems/thread ------------------------------------
__global__ void cast_bf16_kernel(const float* __restrict__ in,
                                 unsigned short* __restrict__ out) {
    const int i = (int)blockIdx.x * 256 + threadIdx.x;
    float4 a = ((const float4*)in)[2 * i];
    float4 b = ((const float4*)in)[2 * i + 1];
    short8 p;
    p[0] = (short)f2bf(a.x); p[1] = (short)f2bf(a.y);
    p[2] = (short)f2bf(a.z); p[3] = (short)f2bf(a.w);
    p[4] = (short)f2bf(b.x); p[5] = (short)f2bf(b.y);
    p[6] = (short)f2bf(b.z); p[7] = (short)f2bf(b.w);
    ((short8*)out)[i] = p;
}

// ---- C[M][N] = A[M][K] @ Wt[N][K]^T + bias ---------------------------------
// grid (NXB, 512); NXB = 1<<xshift column blocks; 256 threads = 4 waves.
template <bool OUT_F32>
__global__ __launch_bounds__(256, 2)
void gemm_kernel(const unsigned short* __restrict__ A, int lda,
                 const unsigned short* __restrict__ Wt,   // bf16 [N][K]
                 const float* __restrict__ bias,          // fp32 [N-local]
                 void* __restrict__ Cv, int ldc,
                 int K, int xshift) {
    constexpr int BK = 64;
    __shared__ __align__(16) unsigned short As[128 * 64];
    __shared__ __align__(16) unsigned short Bs[128 * 64];
    const int t = threadIdx.x;
    const int wave = t >> 6, lane = t & 63;
    const int lm = lane & 15, quad = lane >> 4;

    // XCD swizzle: all column blocks of one row panel -> same XCD's L2.
    const int NXB = 1 << xshift;
    const int lin = (int)blockIdx.x + ((int)blockIdx.y << xshift);
    const int xcd = lin & 7, slot = lin >> 3;
    const int by = xcd * 64 + (slot >> xshift);   // gridDim.y == 512
    const int bx = slot & (NXB - 1);
    const int row0 = by * 128, n0 = bx * 128;
    const int wm = (wave & 1) * 64, wn = (wave >> 1) * 64;

    // staging: slot s = it*256 + t; row r = s>>3; chunk-slot = t&7;
    // fetch global chunk (slot ^ (r&7)) so LDS chunk c holds col (c ^ (r&7)).
    const int arow = t >> 3;                 // row within 32-row group
    const int cb = (t & 7) ^ (arow & 7);     // swizzled source chunk
    const unsigned short* Ag = A + (size_t)(row0 + arow) * lda + cb * 8;
    const unsigned short* Bg = Wt + (size_t)(n0 + arow) * K + cb * 8;

    floatx4 acc[4][4] = {};

    for (int kb = 0; kb < K; kb += BK) {
        __syncthreads();   // previous iteration's ds_reads done
#pragma unroll
        for (int it = 0; it < 4; ++it) {
            async_cp16(Ag + kb + (size_t)(it * 32) * lda,
                       &As[(it * 256 + wave * 64) * 8]);
            async_cp16(Bg + kb + (size_t)(it * 32) * K,
                       &Bs[(it * 256 + wave * 64) * 8]);
        }
        __syncthreads();   // drains vmcnt before barrier (compiler-emitted)
#pragma unroll
        for (int kk = 0; kk < 2; ++kk) {
            short8 af[4], bfv[4];
            const int cfrag = kk * 4 + quad;
            const int csw = cfrag ^ (lm & 7);   // r&7 == lm&7 for all frags
#pragma unroll
            for (int mi = 0; mi < 4; ++mi)
                af[mi] = *(const short8*)&As[(wm + mi * 16 + lm) * 64 + csw * 8];
#pragma unroll
            for (int ni = 0; ni < 4; ++ni)
                bfv[ni] = *(const short8*)&Bs[(wn + ni * 16 + lm) * 64 + csw * 8];
#pragma unroll
            for (int mi = 0; mi < 4; ++mi)
#pragma unroll
                for (int ni = 0; ni < 4; ++ni)
                    acc[mi][ni] = __builtin_amdgcn_mfma_f32_16x16x32_bf16(
                        af[mi], bfv[ni], acc[mi][ni], 0, 0, 0);
        }
    }
    // ---- epilogue: D lane layout col=lane&15, row=quad*4+r ----
#pragma unroll
    for (int ni = 0; ni < 4; ++ni) {
        int col = n0 + wn + ni * 16 + lm;
        float bv = bias[col];
#pragma unroll
        for (int mi = 0; mi < 4; ++mi) {
            int rowb = row0 + wm + mi * 16 + quad * 4;
#pragma unroll
            for (int r = 0; r < 4; ++r) {
                float v = acc[mi][ni][r] + bv;
                if (OUT_F32)
                    ((float*)Cv)[(size_t)(rowb + r) * ldc + col] = v;
                else
                    ((unsigned short*)Cv)[(size_t)(rowb + r) * ldc + col] = f2bf(v);
            }
        }
    }
}

// ---- attention: one wave per (batch, head); lane = dh index ---------------
// qkv bf16 [65536][1536] = [q | k | v]; result overwrites q slots.
__global__ __launch_bounds__(256)
void attn_kernel(unsigned short* __restrict__ qkv) {
    const int t = threadIdx.x;
    const int wave = t >> 6, lane = t & 63;
    const int bh = (int)blockIdx.x * 4 + wave;  // b*8 + h
    const int b = bh >> 3, h = bh & 7;
    const float scale = 0.044194173824159216f;  // 512^-0.5
    const size_t base = (size_t)b * 4 * 1536 + h * 64 + lane;
    float qv[4], kk4[4], vv[4];
#pragma unroll
    for (int i = 0; i < 4; ++i) {
        qv[i]  = bf2f(qkv[base + (size_t)i * 1536]);
        kk4[i] = bf2f(qkv[base + (size_t)i * 1536 + 512]);
        vv[i]  = bf2f(qkv[base + (size_t)i * 1536 + 1024]);
    }
    float s[4][4];
#pragma unroll
    for (int i = 0; i < 4; ++i)
#pragma unroll
        for (int j = 0; j < 4; ++j) {
            float v = qv[i] * kk4[j];
#pragma unroll
            for (int off = 32; off > 0; off >>= 1) v += __shfl_xor(v, off, 64);
            s[i][j] = v * scale;
        }
    const float Mm[4][4] = {{1,1,1,0},{1,1,0,1},{1,0,1,1},{0,1,1,1}};
    const float Pp[4][4] = {{0,0,0,-1.6f},{0,0,-1.2f,0},{0,-0.8f,0,0},{-0.4f,0,0,0}};
#pragma unroll
    for (int i = 0; i < 4; ++i) {
        float tj[4], mx = -1e30f;
#pragma unroll
        for (int j = 0; j < 4; ++j) {
            tj[j] = s[i][j] * Mm[i][j] + Pp[i][j];
            mx = fmaxf(mx, tj[j]);
        }
        float e[4], sum = 0.f;
#pragma unroll
        for (int j = 0; j < 4; ++j) { e[j] = __expf(tj[j] - mx); sum += e[j]; }
        float inv = 1.f / sum;
        float od = 0.f;
#pragma unroll
        for (int j = 0; j < 4; ++j) od += e[j] * Mm[i][j] * vv[j];
        qkv[base + (size_t)i * 1536] = f2bf(od * inv);
    }
}

// ---------------------------------------------------------------------------
extern "C" void kernel_launch(void* const* d_in, const int* in_sizes, int n_in,
                              void* d_out, int out_size, void* d_ws, size_t ws_size,
                              hipStream_t stream) {
    const float* x   = (const float*)d_in[0];
    const float* ctx = (const float*)d_in[1];
    const float* Wq  = (const float*)d_in[2];
    const float* bq  = (const float*)d_in[3];
    const float* Wkv = (const float*)d_in[4];
    const float* bkv = (const float*)d_in[5];
    const float* Wo  = (const float*)d_in[6];
    const float* bo  = (const float*)d_in[7];
    float* out = (float*)d_out;

    const int M = 65536;  // B*N rows
    unsigned short* WqkvT = (unsigned short*)d_ws;          // 1536*512
    unsigned short* WoT   = WqkvT + 1536 * 512;             // 512*512
    unsigned short* abf   = WoT + 512 * 512;                // M*512 (x, then ctx)
    unsigned short* qkv   = abf + (size_t)M * 512;          // M*1536

    dim3 b256(256);
    transpose_cast_kernel<<<dim3(16, 16), b256, 0, stream>>>(Wq, WqkvT, 512, 512);
    transpose_cast_kernel<<<dim3(16, 32), b256, 0, stream>>>(Wkv, WqkvT + 512 * 512, 512, 1024);
    transpose_cast_kernel<<<dim3(16, 16), b256, 0, stream>>>(Wo, WoT, 512, 512);

    // q = xbf @ WqT + bq
    cast_bf16_kernel<<<dim3(M * 512 / (8 * 256)), b256, 0, stream>>>(x, abf);
    gemm_kernel<false><<<dim3(4, 512), b256, 0, stream>>>(
        abf, 512, WqkvT, bq, qkv, 1536, 512, 2);

    // kv = ctxbf @ WkvT + bkv (reuse abf after q-GEMM consumed it)
    cast_bf16_kernel<<<dim3(M * 512 / (8 * 256)), b256, 0, stream>>>(ctx, abf);
    gemm_kernel<false><<<dim3(8, 512), b256, 0, stream>>>(
        abf, 512, WqkvT + 512 * 512, bkv, qkv + 512, 1536, 512, 3);

    attn_kernel<<<dim3(M * 8 / 16), b256, 0, stream>>>(qkv);

    // out = attnout @ WoT + bo
    gemm_kernel<true><<<dim3(4, 512), b256, 0, stream>>>(
        qkv, 1536, WoT, bo, out, 512, 512, 2);
}